// Round 1
// 331.977 us; speedup vs baseline: 1.0207x; 1.0207x over previous
//
#include <hip/hip_runtime.h>
#include <hip/hip_bf16.h>
#include <hip/hip_fp16.h>

// Problem constants
#define BATCH 64
#define C_IN 16
#define T0 8192
#define T1 4096   // after pool1
#define T2 2048   // after pool2 (nodes per batch)
#define N_NODES (BATCH * T2)   // 131072
#define HID 64
#define NOUT 10

// Coarse-bucket edge partition parameters
#define NCB 256
#define CB_SHIFT 9
#define CB_TGT 512
#define RCAP 9216
#define PC_EDGES 2048
#define PC_CAP 28

// packed edge record: bits[0:17) = source r, bits[17:26) = local col
#define PK_RMASK 0x1FFFF

// per-block staged edge-span capacity
#define EC 1024

// zero-row index (tables have N_NODES+1 rows; row N_NODES is all zeros)
#define ZROW N_NODES

typedef __fp16 half8 __attribute__((ext_vector_type(8)));
typedef __fp16 half4v __attribute__((ext_vector_type(4)));
typedef float floatx4 __attribute__((ext_vector_type(4)));

// ---------------- conv1: [64,16,8192] -> relu -> pool2 -> h1 fp16 [64,16,4096]
__global__ __launch_bounds__(256) void conv1_kernel(const float* __restrict__ x,
    const float* __restrict__ w, const float* __restrict__ bias,
    __fp16* __restrict__ h1) {
  __shared__ float xs[16 * 520];
  int b = blockIdx.x >> 4;
  int tp0 = (blockIdx.x & 15) * 256;
  int t_base = tp0 * 2 - 2;
  const float* xb = x + (size_t)b * C_IN * T0;
  for (int idx = threadIdx.x; idx < 16 * 516; idx += 256) {
    int ci = idx / 516;
    int off = idx - ci * 516;
    int gt = t_base + off;
    float v = 0.f;
    if (gt >= 0 && gt < T0) v = xb[ci * T0 + gt];
    xs[ci * 520 + off] = v;
  }
  __syncthreads();
  int tp = threadIdx.x;
  float acc0[16], acc1[16];
#pragma unroll
  for (int co = 0; co < 16; ++co) { acc0[co] = 0.f; acc1[co] = 0.f; }
#pragma unroll 4
  for (int ci = 0; ci < 16; ++ci) {
    float xv[6];
#pragma unroll
    for (int k = 0; k < 6; ++k) xv[k] = xs[ci * 520 + 2 * tp + k];
#pragma unroll
    for (int co = 0; co < 16; ++co) {
#pragma unroll
      for (int k = 0; k < 5; ++k) {
        float wv = w[(co * 16 + ci) * 5 + k];
        acc0[co] += xv[k] * wv;
        acc1[co] += xv[k + 1] * wv;
      }
    }
  }
#pragma unroll
  for (int co = 0; co < 16; ++co) {
    float v = fmaxf(acc0[co], acc1[co]) + bias[co];
    v = fmaxf(v, 0.f);
    h1[((size_t)b * 16 + co) * T1 + tp0 + tp] = (__fp16)v;
  }
}

// ---------------- conv2 + gemm1 fused: h1 -> relu/pool -> (LDS) -> MFMA @W1
__global__ __launch_bounds__(256) void conv2_gemm1(const __fp16* __restrict__ h1,
    const float* __restrict__ w, const float* __restrict__ bias,
    const float* __restrict__ W1, const float* __restrict__ dis,
    __fp16* __restrict__ xw) {
  __shared__ float xs[16 * 520];
  __shared__ __fp16 fs[256 * 40];
  int b = blockIdx.x >> 3;
  int tp0 = (blockIdx.x & 7) * 256;
  int t_base = tp0 * 2 - 2;
  const __fp16* xb = h1 + (size_t)b * 16 * T1;
  for (int idx = threadIdx.x; idx < 16 * 516; idx += 256) {
    int ci = idx / 516;
    int off = idx - ci * 516;
    int gt = t_base + off;
    float v = 0.f;
    if (gt >= 0 && gt < T1) v = (float)xb[ci * T1 + gt];
    xs[ci * 520 + off] = v;
  }
  __syncthreads();
  int tp = threadIdx.x;
  float acc0[32], acc1[32];
#pragma unroll
  for (int co = 0; co < 32; ++co) { acc0[co] = 0.f; acc1[co] = 0.f; }
#pragma unroll 2
  for (int ci = 0; ci < 16; ++ci) {
    float xv[6];
#pragma unroll
    for (int k = 0; k < 6; ++k) xv[k] = xs[ci * 520 + 2 * tp + k];
#pragma unroll
    for (int co = 0; co < 32; ++co) {
#pragma unroll
      for (int k = 0; k < 5; ++k) {
        float wv = w[(co * 16 + ci) * 5 + k];
        acc0[co] += xv[k] * wv;
        acc1[co] += xv[k + 1] * wv;
      }
    }
  }
  half8 hres[4];
#pragma unroll
  for (int co = 0; co < 32; ++co) {
    float v = fmaxf(acc0[co], acc1[co]) + bias[co];
    hres[co >> 3][co & 7] = (__fp16)fmaxf(v, 0.f);
  }
  half8* frow = (half8*)(fs + tp * 40);
#pragma unroll
  for (int j = 0; j < 4; ++j) frow[j] = hres[j];
  __syncthreads();
  int lane = threadIdx.x & 63;
  int m = lane & 15;
  int q = lane >> 4;
  int wib = threadIdx.x >> 6;
  half8 bf[4];
#pragma unroll
  for (int t = 0; t < 4; ++t)
#pragma unroll
    for (int j = 0; j < 8; ++j)
      bf[t][j] = (__fp16)W1[(q * 8 + j) * 64 + t * 16 + m];
  int gnode0 = b * T2 + tp0;
#pragma unroll
  for (int tt = 0; tt < 4; ++tt) {
    int lbase = (wib * 4 + tt) * 16;
    half8 a = *(const half8*)(fs + (lbase + m) * 40 + q * 8);
    float d[4];
#pragma unroll
    for (int r = 0; r < 4; ++r) d[r] = dis[gnode0 + lbase + q * 4 + r];
#pragma unroll
    for (int t = 0; t < 4; ++t) {
      floatx4 acc = {0.f, 0.f, 0.f, 0.f};
      acc = __builtin_amdgcn_mfma_f32_16x16x32_f16(a, bf[t], acc, 0, 0, 0);
#pragma unroll
      for (int r = 0; r < 4; ++r)
        xw[(size_t)(gnode0 + lbase + q * 4 + r) * 64 + t * 16 + m] = (__fp16)(acc[r] * d[r]);
    }
  }
}

// ---------------- pass C: partition edges (packed 4B records) into bucket regions
__global__ __launch_bounds__(256) void partition_pairs(const int* __restrict__ ei, int E,
    int* __restrict__ rcnt, int* __restrict__ gpairs) {
  __shared__ int lcnt[NCB];
  __shared__ int lpk[NCB * PC_CAP];
  if (threadIdx.x < NCB) lcnt[threadIdx.x] = 0;
  __syncthreads();
  int e0 = blockIdx.x * PC_EDGES;
#pragma unroll
  for (int j = 0; j < PC_EDGES / 256; ++j) {
    int e = e0 + j * 256 + threadIdx.x;
    if (e < E) {
      int r = ei[e];
      int c = ei[E + e];
      int cb = c >> CB_SHIFT;
      int pk = r | ((c & (CB_TGT - 1)) << 17);
      int slot = atomicAdd(&lcnt[cb], 1);
      if (slot < PC_CAP) {
        lpk[cb * PC_CAP + slot] = pk;
      } else {
        int pos = atomicAdd(&rcnt[cb], 1);
        if (pos < RCAP) gpairs[(size_t)cb * RCAP + pos] = pk;
      }
    }
  }
  __syncthreads();
  int t = threadIdx.x;
  if (t < NCB) {
    int n = lcnt[t];
    if (n > PC_CAP) n = PC_CAP;
    if (n > 0) {
      int base = atomicAdd(&rcnt[t], n);
      int* dst = gpairs + (size_t)t * RCAP;
      for (int k = 0; k < n; ++k) {
        int p = base + k;
        if (p < RCAP) dst[p] = lpk[t * PC_CAP + k];
      }
    }
  }
}

// ---------------- pass D: per coarse bucket, exact-degree CSR via wave-scans
__global__ __launch_bounds__(512) void build_csr(const int* __restrict__ gpairs,
    const int* __restrict__ rcnt, int* __restrict__ ebuf,
    int* __restrict__ estart, int* __restrict__ ecnt, float* __restrict__ dis) {
  __shared__ int deg[CB_TGT];
  __shared__ int cur[CB_TGT];
  __shared__ int sc[CB_TGT];
  __shared__ int wsum[8];
  int b = blockIdx.x;
  int t = threadIdx.x;
  deg[t] = 0;
  cur[t] = 0;
  __syncthreads();
  int m = rcnt[b];
  if (m > RCAP) m = RCAP;
  const int* reg = gpairs + (size_t)b * RCAP;
  for (int k = t; k < m; k += 512)
    atomicAdd(&deg[(reg[k] >> 17) & (CB_TGT - 1)], 1);
  __syncthreads();
  int d = deg[t];
  int lane = t & 63;
  int wv = t >> 6;
  int sum = d;
#pragma unroll
  for (int off = 1; off < 64; off <<= 1) {
    int v = __shfl_up(sum, off, 64);
    if (lane >= off) sum += v;
  }
  if (lane == 63) wsum[wv] = sum;
  __syncthreads();
  int prefix = 0;
#pragma unroll
  for (int i = 0; i < 8; ++i) prefix += (i < wv) ? wsum[i] : 0;
  int excl = prefix + sum - d;
  int gi = (b << CB_SHIFT) + t;
  int base = b * RCAP;
  estart[gi] = base + excl;
  ecnt[gi] = d;
  dis[gi] = rsqrtf((float)d + 1.0f);
  sc[t] = excl;
  __syncthreads();
  for (int k = t; k < m; k += 512) {
    int p = reg[k];
    int lc = (p >> 17) & (CB_TGT - 1);
    int off = atomicAdd(&cur[lc], 1);
    ebuf[base + sc[lc] + off] = p & PK_RMASK;
  }
}

// ======== gather macro: staged edge span, 16-edge windows.
// wave layout: es = lane>>4 (4 edge slots), ch = lane&15 (4 feats each).
// Full windows (c>>4) carry NO bounds checks (c is wave-uniform -> scalar
// branch); only the single tail window selects the zero row per slot.
// Accumulation: 2-level packed-fp16 tree (v_pk_add_f16) then 4 cvt + 4 f32 add.
// ebuf entries are pre-masked row indices; address = 32-bit byte offset
// (r<<7 | ch*8) so loads take the saddr+voffset form.
#define GATHER_NODE(c_, stl_, AX, AY, AZ, AW)                                   \
  {                                                                             \
    int sb_ = (stl_) + es;                                                      \
    int nf_ = (c_) >> 4;                                                        \
    for (int it = 0; it < nf_; ++it) {                                          \
      half4v h[4];                                                              \
      _Pragma("unroll")                                                         \
      for (int j = 0; j < 4; ++j) {                                             \
        unsigned r = (unsigned)sidx[sb_ + (it << 4) + j * 4];                   \
        h[j] = *(const half4v*)((const char*)tab + ((r << 7) + ch8));           \
      }                                                                         \
      half4v s01_ = h[0] + h[1];                                                \
      half4v s23_ = h[2] + h[3];                                                \
      half4v sv_ = s01_ + s23_;                                                 \
      AX += (float)sv_[0]; AY += (float)sv_[1];                                 \
      AZ += (float)sv_[2]; AW += (float)sv_[3];                                 \
    }                                                                           \
    if ((c_) & 15) {                                                            \
      int s0_ = nf_ << 4;                                                       \
      half4v h[4];                                                              \
      _Pragma("unroll")                                                         \
      for (int j = 0; j < 4; ++j) {                                             \
        int k = s0_ + j * 4 + es;                                               \
        unsigned r = (unsigned)sidx[(stl_) + k];                                \
        unsigned off = (k < (c_)) ? ((r << 7) + ch8) : zoff;                    \
        h[j] = *(const half4v*)((const char*)tab + off);                        \
      }                                                                         \
      half4v s01_ = h[0] + h[1];                                                \
      half4v s23_ = h[2] + h[3];                                                \
      half4v sv_ = s01_ + s23_;                                                 \
      AX += (float)sv_[0]; AY += (float)sv_[1];                                 \
      AZ += (float)sv_[2]; AW += (float)sv_[3];                                 \
    }                                                                           \
  }

// ---------------- agg1 + gemm2 fused (fp16 tables, staged edge span)
__global__ __launch_bounds__(256) void agg1_gemm2(const __fp16* __restrict__ tab,
    const int* __restrict__ ebuf, const int* __restrict__ estart,
    const int* __restrict__ ecnt, const float* __restrict__ dis,
    const float* __restrict__ bias, const float* __restrict__ W2,
    __fp16* __restrict__ xw2, int N) {
  __shared__ __fp16 g1s[16 * 72];
  __shared__ int sidx[EC + 16];   // +16: tail window may over-read in-bounds
  __shared__ int sst[16], scn[16];
  int t = threadIdx.x;
  int base16 = blockIdx.x * 16;
  if (t < 16) {
    sst[t] = estart[base16 + t];
    scn[t] = ecnt[base16 + t];
  }
  __syncthreads();
  int span0 = sst[0];
  int total = sst[15] + scn[15] - span0;
  if (total > EC) total = EC;
  for (int k = t; k < total; k += 256) sidx[k] = ebuf[span0 + k];
  __syncthreads();
  int lane = t & 63;
  int es = lane >> 4;
  int ch = lane & 15;
  int wib = t >> 6;
  unsigned ch8 = (unsigned)ch * 8u;
  unsigned zoff = ((unsigned)ZROW << 7) + ch8;
  float4 bv = *(const float4*)(bias + ch * 4);
#pragma unroll
  for (int jj = 0; jj < 4; ++jj) {
    int il = wib * 4 + jj;
    int i = base16 + il;
    int stl = sst[il] - span0;
    int c = scn[il];
    if (stl + c > EC) c = (EC > stl) ? (EC - stl) : 0;
    float di = dis[i];
    float ax = 0.f, ay = 0.f, az = 0.f, aw = 0.f;
    GATHER_NODE(c, stl, ax, ay, az, aw)
    ax += __shfl_xor(ax, 16, 64); ax += __shfl_xor(ax, 32, 64);
    ay += __shfl_xor(ay, 16, 64); ay += __shfl_xor(ay, 32, 64);
    az += __shfl_xor(az, 16, 64); az += __shfl_xor(az, 32, 64);
    aw += __shfl_xor(aw, 16, 64); aw += __shfl_xor(aw, 32, 64);
    half4v hs = *(const half4v*)(tab + (size_t)i * 64 + ch * 4);
    if (es == 0) {
      half4v r;
      r[0] = (__fp16)fmaxf((ax + (float)hs[0]) * di + bv.x, 0.f);
      r[1] = (__fp16)fmaxf((ay + (float)hs[1]) * di + bv.y, 0.f);
      r[2] = (__fp16)fmaxf((az + (float)hs[2]) * di + bv.z, 0.f);
      r[3] = (__fp16)fmaxf((aw + (float)hs[3]) * di + bv.w, 0.f);
      *(half4v*)(g1s + il * 72 + ch * 4) = r;
    }
  }
  __syncthreads();
  // gemm2 epilogue: wave wib computes output columns wib*16..wib*16+15
  int m = lane & 15;
  int q = lane >> 4;
  half8 b0, b1;
#pragma unroll
  for (int j = 0; j < 8; ++j) {
    b0[j] = (__fp16)W2[(q * 8 + j) * 64 + wib * 16 + m];
    b1[j] = (__fp16)W2[(32 + q * 8 + j) * 64 + wib * 16 + m];
  }
  half8 a0 = *(const half8*)(g1s + m * 72 + q * 8);
  half8 a1 = *(const half8*)(g1s + m * 72 + 32 + q * 8);
  floatx4 acc = {0.f, 0.f, 0.f, 0.f};
  acc = __builtin_amdgcn_mfma_f32_16x16x32_f16(a0, b0, acc, 0, 0, 0);
  acc = __builtin_amdgcn_mfma_f32_16x16x32_f16(a1, b1, acc, 0, 0, 0);
#pragma unroll
  for (int r = 0; r < 4; ++r) {
    int node = base16 + q * 4 + r;
    xw2[(size_t)node * 64 + wib * 16 + m] = (__fp16)(acc[r] * dis[node]);
  }
}

// ---------------- GCN aggregate layer-2 (fp16 table, staged span) + mean-pool
__global__ __launch_bounds__(256) void gcn_aggregate_pool(const __fp16* __restrict__ tab,
    const int* __restrict__ ebuf, const int* __restrict__ estart,
    const int* __restrict__ ecnt, const float* __restrict__ dis,
    const float* __restrict__ bias, float* __restrict__ pool, int N) {
  __shared__ float4 red[4][16];
  __shared__ int sidx[EC + 16];   // +16: tail window may over-read in-bounds
  __shared__ int sst[16], scn[16];
  int t = threadIdx.x;
  int base16 = blockIdx.x * 16;
  if (t < 16) {
    sst[t] = estart[base16 + t];
    scn[t] = ecnt[base16 + t];
  }
  __syncthreads();
  int span0 = sst[0];
  int total = sst[15] + scn[15] - span0;
  if (total > EC) total = EC;
  for (int k = t; k < total; k += 256) sidx[k] = ebuf[span0 + k];
  __syncthreads();
  int lane = t & 63;
  int es = lane >> 4;
  int ch = lane & 15;
  int wib = t >> 6;
  unsigned ch8 = (unsigned)ch * 8u;
  unsigned zoff = ((unsigned)ZROW << 7) + ch8;
  float4 bv = *(const float4*)(bias + ch * 4);
  float px = 0.f, py = 0.f, pz = 0.f, pw = 0.f;
#pragma unroll
  for (int jj = 0; jj < 4; ++jj) {
    int il = wib * 4 + jj;
    int i = base16 + il;
    int stl = sst[il] - span0;
    int c = scn[il];
    if (stl + c > EC) c = (EC > stl) ? (EC - stl) : 0;
    float di = dis[i];
    float ax = 0.f, ay = 0.f, az = 0.f, aw = 0.f;
    GATHER_NODE(c, stl, ax, ay, az, aw)
    ax += __shfl_xor(ax, 16, 64); ax += __shfl_xor(ax, 32, 64);
    ay += __shfl_xor(ay, 16, 64); ay += __shfl_xor(ay, 32, 64);
    az += __shfl_xor(az, 16, 64); az += __shfl_xor(az, 32, 64);
    aw += __shfl_xor(aw, 16, 64); aw += __shfl_xor(aw, 32, 64);
    half4v hs = *(const half4v*)(tab + (size_t)i * 64 + ch * 4);
    px += fmaxf((ax + (float)hs[0]) * di + bv.x, 0.f);
    py += fmaxf((ay + (float)hs[1]) * di + bv.y, 0.f);
    pz += fmaxf((az + (float)hs[2]) * di + bv.z, 0.f);
    pw += fmaxf((aw + (float)hs[3]) * di + bv.w, 0.f);
  }
  if (es == 0) red[wib][ch] = make_float4(px, py, pz, pw);
  __syncthreads();
  if (threadIdx.x < 64) {
    int f = threadIdx.x;
    int c4 = f >> 2, j4 = f & 3;
    const float* r0 = (const float*)&red[0][c4];
    const float* r1 = (const float*)&red[1][c4];
    const float* r2 = (const float*)&red[2][c4];
    const float* r3 = (const float*)&red[3][c4];
    float sum = r0[j4] + r1[j4] + r2[j4] + r3[j4];
    int b = (blockIdx.x * 16) >> 11;
    atomicAdd(&pool[b * 64 + f], sum);
  }
}

// ---------------- classifier: out[b] = (pool[b]/2048) @ cls_w + cls_b
__global__ __launch_bounds__(64) void classify(const float* __restrict__ pool,
    const float* __restrict__ cw, const float* __restrict__ cb,
    float* __restrict__ out) {
  __shared__ float pl[64];
  int b = blockIdx.x;
  int t = threadIdx.x;
  pl[t] = pool[b * 64 + t] * (1.0f / (float)T2);
  __syncthreads();
  if (t < NOUT) {
    float a = cb[t];
#pragma unroll
    for (int k = 0; k < 64; ++k) a += pl[k] * cw[k * NOUT + t];
    out[b * NOUT + t] = a;
  }
}

extern "C" void kernel_launch(void* const* d_in, const int* in_sizes, int n_in,
                              void* d_out, int out_size, void* d_ws, size_t ws_size,
                              hipStream_t stream) {
  const float* x    = (const float*)d_in[0];
  const int*   ei   = (const int*)d_in[1];
  const float* c1w  = (const float*)d_in[2];
  const float* c1b  = (const float*)d_in[3];
  const float* c2w  = (const float*)d_in[4];
  const float* c2b  = (const float*)d_in[5];
  const float* g1w  = (const float*)d_in[6];
  const float* g1b  = (const float*)d_in[7];
  const float* g2w  = (const float*)d_in[8];
  const float* g2b  = (const float*)d_in[9];
  const float* cw   = (const float*)d_in[10];
  const float* cb   = (const float*)d_in[11];
  float* out = (float*)d_out;
  int E = in_sizes[1] / 2;
  const int N = N_NODES;

  // workspace layout (bytes); xw/xw2 have N+1 rows (last = zero row)
  char* ws = (char*)d_ws;
  int*    gpairs = (int*)(ws);                     //  9,437,184 (packed 4B)
  int*    ebuf   = (int*)(ws + 9437184);           //  9,437,184
  int*    rcnt   = (int*)(ws + 18874368);          //      4,096
  int*    estart = (int*)(ws + 18878464);          //    524,288
  int*    ecnt   = (int*)(ws + 19402752);          //    524,288
  float*  dis    = (float*)(ws + 19927040);        //    524,288
  float*  pool   = (float*)(ws + 20451328);        //     16,384
  __fp16* xw     = (__fp16*)(ws + 20467712);       // 16,777,472 (N+1 rows fp16)
  __fp16* xw2    = (__fp16*)(ws + 37245184);       // 16,777,472
  __fp16* h1     = (__fp16*)(ws + 54022656);       //  8,388,608

  hipMemsetAsync(rcnt, 0, NCB * sizeof(int), stream);
  hipMemsetAsync(pool, 0, BATCH * HID * sizeof(float), stream);
  hipMemsetAsync(xw + (size_t)N * 64, 0, 128, stream);   // zero row
  hipMemsetAsync(xw2 + (size_t)N * 64, 0, 128, stream);  // zero row

  conv1_kernel<<<dim3(BATCH * 16), dim3(256), 0, stream>>>(x, c1w, c1b, h1);
  partition_pairs<<<dim3((E + PC_EDGES - 1) / PC_EDGES), dim3(256), 0, stream>>>(ei, E, rcnt, gpairs);
  build_csr<<<dim3(NCB), dim3(512), 0, stream>>>(gpairs, rcnt, ebuf, estart, ecnt, dis);

  conv2_gemm1<<<dim3(BATCH * 8), dim3(256), 0, stream>>>(h1, c2w, c2b, g1w, dis, xw);
  agg1_gemm2<<<dim3(N / 16), dim3(256), 0, stream>>>(xw, ebuf, estart, ecnt, dis, g1b, g2w, xw2, N);
  gcn_aggregate_pool<<<dim3(N / 16), dim3(256), 0, stream>>>(xw2, ebuf, estart, ecnt, dis, g2b, pool, N);

  classify<<<dim3(BATCH), dim3(64), 0, stream>>>(pool, cw, cb, out);
}

// Round 2
// 283.975 us; speedup vs baseline: 1.1933x; 1.1690x over previous
//
#include <hip/hip_runtime.h>
#include <hip/hip_bf16.h>
#include <hip/hip_fp16.h>

// Problem constants
#define BATCH 64
#define C_IN 16
#define T0 8192
#define T1 4096   // after pool1
#define T2 2048   // after pool2 (nodes per batch)
#define N_NODES (BATCH * T2)   // 131072
#define HID 64
#define NOUT 10

// Coarse-bucket edge partition parameters
#define NCB 256
#define CB_SHIFT 9
#define CB_TGT 512
#define RCAP 9216
#define PC_EDGES 2048
#define PC_CAP 28

// packed edge record: bits[0:17) = source r, bits[17:26) = local col
#define PK_RMASK 0x1FFFF

// per-block staged edge-span capacity
#define EC 1024

// zero-row index (tables have N_NODES+1 rows; row N_NODES is all zeros)
#define ZROW N_NODES

// transposed conv-input LDS tile: row = position, 16 ci halves + pad.
// ROWW=24 halves (48B = 12 words): b128 reads at pos*12 words tile all 32
// banks (stride-12 start-bank cycle {0,12,24,4,16,28,8,20} -> 2-way = free).
#define ROWW 24

typedef __fp16 half8 __attribute__((ext_vector_type(8)));
typedef __fp16 half4v __attribute__((ext_vector_type(4)));
typedef float floatx4 __attribute__((ext_vector_type(4)));

// ---------------- conv1 (MFMA): x fp32 -> im2col GEMM (K=80 pad 96, N=16co)
// -> bias/relu/pool in-register -> h1 fp16 [b][T1][16ci] (position-major!)
__global__ __launch_bounds__(256) void conv1_kernel(const float* __restrict__ x,
    const float* __restrict__ w, const float* __restrict__ bias,
    __fp16* __restrict__ h1) {
  __shared__ __fp16 xs[528 * ROWW];
  int b = blockIdx.x >> 4;
  int tp0 = (blockIdx.x & 15) * 256;          // pooled positions [tp0, tp0+256)
  int t_base = 2 * tp0 - 8;                    // xs[p] = x[t_base + p]; A-read +6 offset
  const float* xb = x + (size_t)b * C_IN * T0;
  // stage 528 positions x 16 ci, fp32->fp16, transposed. float4 chunks are
  // 4-aligned (t_base % 4 == 0) and never partially OOB (T0 % 4 == 0).
  for (int idx = threadIdx.x; idx < 16 * 132; idx += 256) {
    int ci = idx & 15;
    int c4 = idx >> 4;
    int gt = t_base + c4 * 4;
    float4 v = make_float4(0.f, 0.f, 0.f, 0.f);
    if (gt >= 0 && gt + 4 <= T0) v = *(const float4*)(xb + ci * T0 + gt);
    __fp16* d = xs + (c4 * 4) * ROWW + ci;
    d[0] = (__fp16)v.x;
    d[ROWW] = (__fp16)v.y;
    d[2 * ROWW] = (__fp16)v.z;
    d[3 * ROWW] = (__fp16)v.w;
  }
  int ln = threadIdx.x & 15;    // A row / B col / C col
  int q = (threadIdx.x & 63) >> 4;
  int wib = threadIdx.x >> 6;
  // B-frag preload: k = q*8+j -> kk = ks*2+(q>>1), ci = (q&1)*8+j; kk==5 -> 0
  half8 wb[3];
#pragma unroll
  for (int ks = 0; ks < 3; ++ks) {
    int kk = ks * 2 + (q >> 1);
#pragma unroll
    for (int j = 0; j < 8; ++j) {
      int ci = (q & 1) * 8 + j;
      float wv = (kk < 5) ? w[(ln * 16 + ci) * 5 + kk] : 0.f;
      wb[ks][j] = (__fp16)wv;
    }
  }
  float bv = bias[ln];
  __syncthreads();
  int qh = q >> 1, qo = (q & 1) * 8;
#pragma unroll 2
  for (int mtl = 0; mtl < 8; ++mtl) {
    int mt = wib * 8 + mtl;
    int posb = mt * 16 + ln + qh + 6;
    half8 a0 = *(const half8*)(xs + posb * ROWW + qo);
    half8 a1 = *(const half8*)(xs + (posb + 2) * ROWW + qo);
    half8 a2 = *(const half8*)(xs + (posb + 4) * ROWW + qo);
    floatx4 c0 = {0.f, 0.f, 0.f, 0.f};
    c0 = __builtin_amdgcn_mfma_f32_16x16x32_f16(a0, wb[0], c0, 0, 0, 0);
    c0 = __builtin_amdgcn_mfma_f32_16x16x32_f16(a1, wb[1], c0, 0, 0, 0);
    c0 = __builtin_amdgcn_mfma_f32_16x16x32_f16(a2, wb[2], c0, 0, 0, 0);
    // C rows q*4+r; pool pairs (0,1),(2,3) -> pooled tp = tp0 + mt*8 + q*2 + {0,1}
    int tp = tp0 + mt * 8 + q * 2;
    size_t o = ((size_t)b * T1 + tp) * 16 + ln;
    h1[o] = (__fp16)fmaxf(fmaxf(c0[0], c0[1]) + bv, 0.f);
    h1[o + 16] = (__fp16)fmaxf(fmaxf(c0[2], c0[3]) + bv, 0.f);
  }
}

// ---------------- conv2 + gemm1 fused (MFMA conv): h1 [b][T1][16] -> conv GEMM
// (K=80 pad 96, N=32co) -> relu/pool -> fs LDS -> MFMA @W1 -> xw
__global__ __launch_bounds__(256) void conv2_gemm1(const __fp16* __restrict__ h1,
    const float* __restrict__ w, const float* __restrict__ bias,
    const float* __restrict__ W1, const float* __restrict__ dis,
    __fp16* __restrict__ xw) {
  __shared__ __fp16 xs[520 * ROWW];
  __shared__ __fp16 fs[256 * 40];
  int b = blockIdx.x >> 3;
  int tp0 = (blockIdx.x & 7) * 256;
  int t_base = 2 * tp0 - 2;                    // xs[p] = h1[b][t_base + p][:]
  // stage: straight 16B-chunk copy (h1 is position-major) with bounds zero-fill
  for (int idx = threadIdx.x; idx < 520 * 2; idx += 256) {
    int row = idx >> 1;
    int hf = idx & 1;
    int gt = t_base + row;
    half8 v;
#pragma unroll
    for (int j = 0; j < 8; ++j) v[j] = (__fp16)0.f;
    if (gt >= 0 && gt < T1) v = *(const half8*)(h1 + ((size_t)b * T1 + gt) * 16 + hf * 8);
    *(half8*)(xs + row * ROWW + hf * 8) = v;
  }
  int ln = threadIdx.x & 15;
  int q = (threadIdx.x & 63) >> 4;
  int wib = threadIdx.x >> 6;
  half8 wb[2][3];
#pragma unroll
  for (int nt = 0; nt < 2; ++nt)
#pragma unroll
    for (int ks = 0; ks < 3; ++ks) {
      int kk = ks * 2 + (q >> 1);
#pragma unroll
      for (int j = 0; j < 8; ++j) {
        int ci = (q & 1) * 8 + j;
        float wv = (kk < 5) ? w[((nt * 16 + ln) * 16 + ci) * 5 + kk] : 0.f;
        wb[nt][ks][j] = (__fp16)wv;
      }
    }
  float b20 = bias[ln];
  float b21 = bias[16 + ln];
  __syncthreads();
  int qh = q >> 1, qo = (q & 1) * 8;
#pragma unroll 2
  for (int mtl = 0; mtl < 8; ++mtl) {
    int mt = wib * 8 + mtl;
    int posb = mt * 16 + ln + qh;
    half8 a0 = *(const half8*)(xs + posb * ROWW + qo);
    half8 a1 = *(const half8*)(xs + (posb + 2) * ROWW + qo);
    half8 a2 = *(const half8*)(xs + (posb + 4) * ROWW + qo);
    floatx4 c0 = {0.f, 0.f, 0.f, 0.f};
    floatx4 c1 = {0.f, 0.f, 0.f, 0.f};
    c0 = __builtin_amdgcn_mfma_f32_16x16x32_f16(a0, wb[0][0], c0, 0, 0, 0);
    c0 = __builtin_amdgcn_mfma_f32_16x16x32_f16(a1, wb[0][1], c0, 0, 0, 0);
    c0 = __builtin_amdgcn_mfma_f32_16x16x32_f16(a2, wb[0][2], c0, 0, 0, 0);
    c1 = __builtin_amdgcn_mfma_f32_16x16x32_f16(a0, wb[1][0], c1, 0, 0, 0);
    c1 = __builtin_amdgcn_mfma_f32_16x16x32_f16(a1, wb[1][1], c1, 0, 0, 0);
    c1 = __builtin_amdgcn_mfma_f32_16x16x32_f16(a2, wb[1][2], c1, 0, 0, 0);
    int node = wib * 64 + mtl * 8 + q * 2;     // wave writes only its own rows
    fs[node * 40 + ln] = (__fp16)fmaxf(fmaxf(c0[0], c0[1]) + b20, 0.f);
    fs[(node + 1) * 40 + ln] = (__fp16)fmaxf(fmaxf(c0[2], c0[3]) + b20, 0.f);
    fs[node * 40 + 16 + ln] = (__fp16)fmaxf(fmaxf(c1[0], c1[1]) + b21, 0.f);
    fs[(node + 1) * 40 + 16 + ln] = (__fp16)fmaxf(fmaxf(c1[2], c1[3]) + b21, 0.f);
  }
  // gemm1 epilogue: wave reads only its own fs rows -> no barrier needed
  half8 bf[4];
#pragma unroll
  for (int t = 0; t < 4; ++t)
#pragma unroll
    for (int j = 0; j < 8; ++j)
      bf[t][j] = (__fp16)W1[(q * 8 + j) * 64 + t * 16 + ln];
  int gnode0 = b * T2 + tp0;
#pragma unroll
  for (int tt = 0; tt < 4; ++tt) {
    int lbase = (wib * 4 + tt) * 16;
    half8 a = *(const half8*)(fs + (lbase + ln) * 40 + q * 8);
    float d[4];
#pragma unroll
    for (int r = 0; r < 4; ++r) d[r] = dis[gnode0 + lbase + q * 4 + r];
#pragma unroll
    for (int t = 0; t < 4; ++t) {
      floatx4 acc = {0.f, 0.f, 0.f, 0.f};
      acc = __builtin_amdgcn_mfma_f32_16x16x32_f16(a, bf[t], acc, 0, 0, 0);
#pragma unroll
      for (int r = 0; r < 4; ++r)
        xw[(size_t)(gnode0 + lbase + q * 4 + r) * 64 + t * 16 + ln] = (__fp16)(acc[r] * d[r]);
    }
  }
}

// ---------------- pass C: partition edges (packed 4B records) into bucket regions
__global__ __launch_bounds__(256) void partition_pairs(const int* __restrict__ ei, int E,
    int* __restrict__ rcnt, int* __restrict__ gpairs) {
  __shared__ int lcnt[NCB];
  __shared__ int lpk[NCB * PC_CAP];
  if (threadIdx.x < NCB) lcnt[threadIdx.x] = 0;
  __syncthreads();
  int e0 = blockIdx.x * PC_EDGES;
#pragma unroll
  for (int j = 0; j < PC_EDGES / 256; ++j) {
    int e = e0 + j * 256 + threadIdx.x;
    if (e < E) {
      int r = ei[e];
      int c = ei[E + e];
      int cb = c >> CB_SHIFT;
      int pk = r | ((c & (CB_TGT - 1)) << 17);
      int slot = atomicAdd(&lcnt[cb], 1);
      if (slot < PC_CAP) {
        lpk[cb * PC_CAP + slot] = pk;
      } else {
        int pos = atomicAdd(&rcnt[cb], 1);
        if (pos < RCAP) gpairs[(size_t)cb * RCAP + pos] = pk;
      }
    }
  }
  __syncthreads();
  int t = threadIdx.x;
  if (t < NCB) {
    int n = lcnt[t];
    if (n > PC_CAP) n = PC_CAP;
    if (n > 0) {
      int base = atomicAdd(&rcnt[t], n);
      int* dst = gpairs + (size_t)t * RCAP;
      for (int k = 0; k < n; ++k) {
        int p = base + k;
        if (p < RCAP) dst[p] = lpk[t * PC_CAP + k];
      }
    }
  }
}

// ---------------- pass D: per coarse bucket, exact-degree CSR via wave-scans
__global__ __launch_bounds__(512) void build_csr(const int* __restrict__ gpairs,
    const int* __restrict__ rcnt, int* __restrict__ ebuf,
    int* __restrict__ estart, int* __restrict__ ecnt, float* __restrict__ dis) {
  __shared__ int deg[CB_TGT];
  __shared__ int cur[CB_TGT];
  __shared__ int sc[CB_TGT];
  __shared__ int wsum[8];
  int b = blockIdx.x;
  int t = threadIdx.x;
  deg[t] = 0;
  cur[t] = 0;
  __syncthreads();
  int m = rcnt[b];
  if (m > RCAP) m = RCAP;
  const int* reg = gpairs + (size_t)b * RCAP;
  for (int k = t; k < m; k += 512)
    atomicAdd(&deg[(reg[k] >> 17) & (CB_TGT - 1)], 1);
  __syncthreads();
  int d = deg[t];
  int lane = t & 63;
  int wv = t >> 6;
  int sum = d;
#pragma unroll
  for (int off = 1; off < 64; off <<= 1) {
    int v = __shfl_up(sum, off, 64);
    if (lane >= off) sum += v;
  }
  if (lane == 63) wsum[wv] = sum;
  __syncthreads();
  int prefix = 0;
#pragma unroll
  for (int i = 0; i < 8; ++i) prefix += (i < wv) ? wsum[i] : 0;
  int excl = prefix + sum - d;
  int gi = (b << CB_SHIFT) + t;
  int base = b * RCAP;
  estart[gi] = base + excl;
  ecnt[gi] = d;
  dis[gi] = rsqrtf((float)d + 1.0f);
  sc[t] = excl;
  __syncthreads();
  for (int k = t; k < m; k += 512) {
    int p = reg[k];
    int lc = (p >> 17) & (CB_TGT - 1);
    int off = atomicAdd(&cur[lc], 1);
    ebuf[base + sc[lc] + off] = p & PK_RMASK;
  }
}

// ======== gather macro: staged edge span, 16-edge windows.
// wave layout: es = lane>>4 (4 edge slots), ch = lane&15 (4 feats each).
// Full windows (c>>4) carry NO bounds checks (c is wave-uniform -> scalar
// branch); only the single tail window selects the zero row per slot.
// Accumulation: 2-level packed-fp16 tree (v_pk_add_f16) then 4 cvt + 4 f32 add.
// ebuf entries are pre-masked row indices; address = 32-bit byte offset
// (r<<7 | ch*8) so loads take the saddr+voffset form.
#define GATHER_NODE(c_, stl_, AX, AY, AZ, AW)                                   \
  {                                                                             \
    int sb_ = (stl_) + es;                                                      \
    int nf_ = (c_) >> 4;                                                        \
    for (int it = 0; it < nf_; ++it) {                                          \
      half4v h[4];                                                              \
      _Pragma("unroll")                                                         \
      for (int j = 0; j < 4; ++j) {                                             \
        unsigned r = (unsigned)sidx[sb_ + (it << 4) + j * 4];                   \
        h[j] = *(const half4v*)((const char*)tab + ((r << 7) + ch8));           \
      }                                                                         \
      half4v s01_ = h[0] + h[1];                                                \
      half4v s23_ = h[2] + h[3];                                                \
      half4v sv_ = s01_ + s23_;                                                 \
      AX += (float)sv_[0]; AY += (float)sv_[1];                                 \
      AZ += (float)sv_[2]; AW += (float)sv_[3];                                 \
    }                                                                           \
    if ((c_) & 15) {                                                            \
      int s0_ = nf_ << 4;                                                       \
      half4v h[4];                                                              \
      _Pragma("unroll")                                                         \
      for (int j = 0; j < 4; ++j) {                                             \
        int k = s0_ + j * 4 + es;                                               \
        unsigned r = (unsigned)sidx[(stl_) + k];                                \
        unsigned off = (k < (c_)) ? ((r << 7) + ch8) : zoff;                    \
        h[j] = *(const half4v*)((const char*)tab + off);                        \
      }                                                                         \
      half4v s01_ = h[0] + h[1];                                                \
      half4v s23_ = h[2] + h[3];                                                \
      half4v sv_ = s01_ + s23_;                                                 \
      AX += (float)sv_[0]; AY += (float)sv_[1];                                 \
      AZ += (float)sv_[2]; AW += (float)sv_[3];                                 \
    }                                                                           \
  }

// ---------------- agg1 + gemm2 fused (fp16 tables, staged edge span)
__global__ __launch_bounds__(256) void agg1_gemm2(const __fp16* __restrict__ tab,
    const int* __restrict__ ebuf, const int* __restrict__ estart,
    const int* __restrict__ ecnt, const float* __restrict__ dis,
    const float* __restrict__ bias, const float* __restrict__ W2,
    __fp16* __restrict__ xw2, int N) {
  __shared__ __fp16 g1s[16 * 72];
  __shared__ int sidx[EC + 16];   // +16: tail window may over-read in-bounds
  __shared__ int sst[16], scn[16];
  int t = threadIdx.x;
  int base16 = blockIdx.x * 16;
  if (t < 16) {
    sst[t] = estart[base16 + t];
    scn[t] = ecnt[base16 + t];
  }
  __syncthreads();
  int span0 = sst[0];
  int total = sst[15] + scn[15] - span0;
  if (total > EC) total = EC;
  for (int k = t; k < total; k += 256) sidx[k] = ebuf[span0 + k];
  __syncthreads();
  int lane = t & 63;
  int es = lane >> 4;
  int ch = lane & 15;
  int wib = t >> 6;
  unsigned ch8 = (unsigned)ch * 8u;
  unsigned zoff = ((unsigned)ZROW << 7) + ch8;
  float4 bv = *(const float4*)(bias + ch * 4);
#pragma unroll
  for (int jj = 0; jj < 4; ++jj) {
    int il = wib * 4 + jj;
    int i = base16 + il;
    int stl = sst[il] - span0;
    int c = scn[il];
    if (stl + c > EC) c = (EC > stl) ? (EC - stl) : 0;
    float di = dis[i];
    float ax = 0.f, ay = 0.f, az = 0.f, aw = 0.f;
    GATHER_NODE(c, stl, ax, ay, az, aw)
    ax += __shfl_xor(ax, 16, 64); ax += __shfl_xor(ax, 32, 64);
    ay += __shfl_xor(ay, 16, 64); ay += __shfl_xor(ay, 32, 64);
    az += __shfl_xor(az, 16, 64); az += __shfl_xor(az, 32, 64);
    aw += __shfl_xor(aw, 16, 64); aw += __shfl_xor(aw, 32, 64);
    half4v hs = *(const half4v*)(tab + (size_t)i * 64 + ch * 4);
    if (es == 0) {
      half4v r;
      r[0] = (__fp16)fmaxf((ax + (float)hs[0]) * di + bv.x, 0.f);
      r[1] = (__fp16)fmaxf((ay + (float)hs[1]) * di + bv.y, 0.f);
      r[2] = (__fp16)fmaxf((az + (float)hs[2]) * di + bv.z, 0.f);
      r[3] = (__fp16)fmaxf((aw + (float)hs[3]) * di + bv.w, 0.f);
      *(half4v*)(g1s + il * 72 + ch * 4) = r;
    }
  }
  __syncthreads();
  // gemm2 epilogue: wave wib computes output columns wib*16..wib*16+15
  int m = lane & 15;
  int q = lane >> 4;
  half8 b0, b1;
#pragma unroll
  for (int j = 0; j < 8; ++j) {
    b0[j] = (__fp16)W2[(q * 8 + j) * 64 + wib * 16 + m];
    b1[j] = (__fp16)W2[(32 + q * 8 + j) * 64 + wib * 16 + m];
  }
  half8 a0 = *(const half8*)(g1s + m * 72 + q * 8);
  half8 a1 = *(const half8*)(g1s + m * 72 + 32 + q * 8);
  floatx4 acc = {0.f, 0.f, 0.f, 0.f};
  acc = __builtin_amdgcn_mfma_f32_16x16x32_f16(a0, b0, acc, 0, 0, 0);
  acc = __builtin_amdgcn_mfma_f32_16x16x32_f16(a1, b1, acc, 0, 0, 0);
#pragma unroll
  for (int r = 0; r < 4; ++r) {
    int node = base16 + q * 4 + r;
    xw2[(size_t)node * 64 + wib * 16 + m] = (__fp16)(acc[r] * dis[node]);
  }
}

// ---------------- GCN aggregate layer-2 (fp16 table, staged span) + mean-pool
__global__ __launch_bounds__(256) void gcn_aggregate_pool(const __fp16* __restrict__ tab,
    const int* __restrict__ ebuf, const int* __restrict__ estart,
    const int* __restrict__ ecnt, const float* __restrict__ dis,
    const float* __restrict__ bias, float* __restrict__ pool, int N) {
  __shared__ float4 red[4][16];
  __shared__ int sidx[EC + 16];   // +16: tail window may over-read in-bounds
  __shared__ int sst[16], scn[16];
  int t = threadIdx.x;
  int base16 = blockIdx.x * 16;
  if (t < 16) {
    sst[t] = estart[base16 + t];
    scn[t] = ecnt[base16 + t];
  }
  __syncthreads();
  int span0 = sst[0];
  int total = sst[15] + scn[15] - span0;
  if (total > EC) total = EC;
  for (int k = t; k < total; k += 256) sidx[k] = ebuf[span0 + k];
  __syncthreads();
  int lane = t & 63;
  int es = lane >> 4;
  int ch = lane & 15;
  int wib = t >> 6;
  unsigned ch8 = (unsigned)ch * 8u;
  unsigned zoff = ((unsigned)ZROW << 7) + ch8;
  float4 bv = *(const float4*)(bias + ch * 4);
  float px = 0.f, py = 0.f, pz = 0.f, pw = 0.f;
#pragma unroll
  for (int jj = 0; jj < 4; ++jj) {
    int il = wib * 4 + jj;
    int i = base16 + il;
    int stl = sst[il] - span0;
    int c = scn[il];
    if (stl + c > EC) c = (EC > stl) ? (EC - stl) : 0;
    float di = dis[i];
    float ax = 0.f, ay = 0.f, az = 0.f, aw = 0.f;
    GATHER_NODE(c, stl, ax, ay, az, aw)
    ax += __shfl_xor(ax, 16, 64); ax += __shfl_xor(ax, 32, 64);
    ay += __shfl_xor(ay, 16, 64); ay += __shfl_xor(ay, 32, 64);
    az += __shfl_xor(az, 16, 64); az += __shfl_xor(az, 32, 64);
    aw += __shfl_xor(aw, 16, 64); aw += __shfl_xor(aw, 32, 64);
    half4v hs = *(const half4v*)(tab + (size_t)i * 64 + ch * 4);
    px += fmaxf((ax + (float)hs[0]) * di + bv.x, 0.f);
    py += fmaxf((ay + (float)hs[1]) * di + bv.y, 0.f);
    pz += fmaxf((az + (float)hs[2]) * di + bv.z, 0.f);
    pw += fmaxf((aw + (float)hs[3]) * di + bv.w, 0.f);
  }
  if (es == 0) red[wib][ch] = make_float4(px, py, pz, pw);
  __syncthreads();
  if (threadIdx.x < 64) {
    int f = threadIdx.x;
    int c4 = f >> 2, j4 = f & 3;
    const float* r0 = (const float*)&red[0][c4];
    const float* r1 = (const float*)&red[1][c4];
    const float* r2 = (const float*)&red[2][c4];
    const float* r3 = (const float*)&red[3][c4];
    float sum = r0[j4] + r1[j4] + r2[j4] + r3[j4];
    int b = (blockIdx.x * 16) >> 11;
    atomicAdd(&pool[b * 64 + f], sum);
  }
}

// ---------------- classifier: out[b] = (pool[b]/2048) @ cls_w + cls_b
__global__ __launch_bounds__(64) void classify(const float* __restrict__ pool,
    const float* __restrict__ cw, const float* __restrict__ cb,
    float* __restrict__ out) {
  __shared__ float pl[64];
  int b = blockIdx.x;
  int t = threadIdx.x;
  pl[t] = pool[b * 64 + t] * (1.0f / (float)T2);
  __syncthreads();
  if (t < NOUT) {
    float a = cb[t];
#pragma unroll
    for (int k = 0; k < 64; ++k) a += pl[k] * cw[k * NOUT + t];
    out[b * NOUT + t] = a;
  }
}

extern "C" void kernel_launch(void* const* d_in, const int* in_sizes, int n_in,
                              void* d_out, int out_size, void* d_ws, size_t ws_size,
                              hipStream_t stream) {
  const float* x    = (const float*)d_in[0];
  const int*   ei   = (const int*)d_in[1];
  const float* c1w  = (const float*)d_in[2];
  const float* c1b  = (const float*)d_in[3];
  const float* c2w  = (const float*)d_in[4];
  const float* c2b  = (const float*)d_in[5];
  const float* g1w  = (const float*)d_in[6];
  const float* g1b  = (const float*)d_in[7];
  const float* g2w  = (const float*)d_in[8];
  const float* g2b  = (const float*)d_in[9];
  const float* cw   = (const float*)d_in[10];
  const float* cb   = (const float*)d_in[11];
  float* out = (float*)d_out;
  int E = in_sizes[1] / 2;
  const int N = N_NODES;

  // workspace layout (bytes); xw/xw2 have N+1 rows (last = zero row)
  char* ws = (char*)d_ws;
  int*    gpairs = (int*)(ws);                     //  9,437,184 (packed 4B)
  int*    ebuf   = (int*)(ws + 9437184);           //  9,437,184
  int*    rcnt   = (int*)(ws + 18874368);          //      4,096
  int*    estart = (int*)(ws + 18878464);          //    524,288
  int*    ecnt   = (int*)(ws + 19402752);          //    524,288
  float*  dis    = (float*)(ws + 19927040);        //    524,288
  float*  pool   = (float*)(ws + 20451328);        //     16,384
  __fp16* xw     = (__fp16*)(ws + 20467712);       // 16,777,472 (N+1 rows fp16)
  __fp16* xw2    = (__fp16*)(ws + 37245184);       // 16,777,472
  __fp16* h1     = (__fp16*)(ws + 54022656);       //  8,388,608 ([b][T1][16] fp16)

  hipMemsetAsync(rcnt, 0, NCB * sizeof(int), stream);
  hipMemsetAsync(pool, 0, BATCH * HID * sizeof(float), stream);
  hipMemsetAsync(xw + (size_t)N * 64, 0, 128, stream);   // zero row
  hipMemsetAsync(xw2 + (size_t)N * 64, 0, 128, stream);  // zero row

  conv1_kernel<<<dim3(BATCH * 16), dim3(256), 0, stream>>>(x, c1w, c1b, h1);
  partition_pairs<<<dim3((E + PC_EDGES - 1) / PC_EDGES), dim3(256), 0, stream>>>(ei, E, rcnt, gpairs);
  build_csr<<<dim3(NCB), dim3(512), 0, stream>>>(gpairs, rcnt, ebuf, estart, ecnt, dis);

  conv2_gemm1<<<dim3(BATCH * 8), dim3(256), 0, stream>>>(h1, c2w, c2b, g1w, dis, xw);
  agg1_gemm2<<<dim3(N / 16), dim3(256), 0, stream>>>(xw, ebuf, estart, ecnt, dis, g1b, g2w, xw2, N);
  gcn_aggregate_pool<<<dim3(N / 16), dim3(256), 0, stream>>>(xw2, ebuf, estart, ecnt, dis, g2b, pool, N);

  classify<<<dim3(BATCH), dim3(64), 0, stream>>>(pool, cw, cb, out);
}

// Round 3
// 263.173 us; speedup vs baseline: 1.2876x; 1.0790x over previous
//
#include <hip/hip_runtime.h>
#include <hip/hip_bf16.h>
#include <hip/hip_fp16.h>

// Problem constants
#define BATCH 64
#define C_IN 16
#define T0 8192
#define T1 4096   // after pool1
#define T2 2048   // after pool2 (nodes per batch)
#define N_NODES (BATCH * T2)   // 131072
#define HID 64
#define NOUT 10

// Coarse-bucket edge partition parameters
#define NCB 256
#define CB_SHIFT 9
#define CB_TGT 512
#define RCAP 9216
#define PC_EDGES 2048
#define PC_CAP 28

// packed edge record: bits[0:17) = source r, bits[17:26) = local col
#define PK_RMASK 0x1FFFF

// per-block staged edge-span capacity
#define EC 1024

// zero-row index (tables have N_NODES+1 rows; row N_NODES is all zeros)
#define ZROW N_NODES

// transposed conv-input LDS tile: row = position, 16 ci halves + pad.
// ROWW=24 halves (48B = 12 words): b128 reads at pos*12 words tile all 32
// banks (stride-12 start-bank cycle {0,12,24,4,16,28,8,20} -> 2-way = free).
#define ROWW 24

// fp8 gather tables: rows scaled by S on store, /S folded into dis at agg.
// |xw| <= ~0.6 -> <=154 scaled: inside e4m3 range with big headroom.
#define FP8_SCALE 256.0f
#define FP8_SINV  (1.0f / 256.0f)

typedef __fp16 half8 __attribute__((ext_vector_type(8)));
typedef __fp16 half4v __attribute__((ext_vector_type(4)));
typedef float floatx4 __attribute__((ext_vector_type(4)));
typedef float floatx2 __attribute__((ext_vector_type(2)));

// ---------------- conv1 (MFMA): x fp32 -> im2col GEMM (K=80 pad 96, N=16co)
// -> bias/relu/pool in-register -> h1 fp16 [b][T1][16ci] (position-major!)
__global__ __launch_bounds__(256) void conv1_kernel(const float* __restrict__ x,
    const float* __restrict__ w, const float* __restrict__ bias,
    __fp16* __restrict__ h1) {
  __shared__ __fp16 xs[528 * ROWW];
  int b = blockIdx.x >> 4;
  int tp0 = (blockIdx.x & 15) * 256;          // pooled positions [tp0, tp0+256)
  int t_base = 2 * tp0 - 8;                    // xs[p] = x[t_base + p]; A-read +6 offset
  const float* xb = x + (size_t)b * C_IN * T0;
  // stage 528 positions x 16 ci, fp32->fp16, transposed. float4 chunks are
  // 4-aligned (t_base % 4 == 0) and never partially OOB (T0 % 4 == 0).
  for (int idx = threadIdx.x; idx < 16 * 132; idx += 256) {
    int ci = idx & 15;
    int c4 = idx >> 4;
    int gt = t_base + c4 * 4;
    float4 v = make_float4(0.f, 0.f, 0.f, 0.f);
    if (gt >= 0 && gt + 4 <= T0) v = *(const float4*)(xb + ci * T0 + gt);
    __fp16* d = xs + (c4 * 4) * ROWW + ci;
    d[0] = (__fp16)v.x;
    d[ROWW] = (__fp16)v.y;
    d[2 * ROWW] = (__fp16)v.z;
    d[3 * ROWW] = (__fp16)v.w;
  }
  int ln = threadIdx.x & 15;    // A row / B col / C col
  int q = (threadIdx.x & 63) >> 4;
  int wib = threadIdx.x >> 6;
  // B-frag preload: k = q*8+j -> kk = ks*2+(q>>1), ci = (q&1)*8+j; kk==5 -> 0
  half8 wb[3];
#pragma unroll
  for (int ks = 0; ks < 3; ++ks) {
    int kk = ks * 2 + (q >> 1);
#pragma unroll
    for (int j = 0; j < 8; ++j) {
      int ci = (q & 1) * 8 + j;
      float wv = (kk < 5) ? w[(ln * 16 + ci) * 5 + kk] : 0.f;
      wb[ks][j] = (__fp16)wv;
    }
  }
  float bv = bias[ln];
  __syncthreads();
  int qh = q >> 1, qo = (q & 1) * 8;
#pragma unroll 2
  for (int mtl = 0; mtl < 8; ++mtl) {
    int mt = wib * 8 + mtl;
    int posb = mt * 16 + ln + qh + 6;
    half8 a0 = *(const half8*)(xs + posb * ROWW + qo);
    half8 a1 = *(const half8*)(xs + (posb + 2) * ROWW + qo);
    half8 a2 = *(const half8*)(xs + (posb + 4) * ROWW + qo);
    floatx4 c0 = {0.f, 0.f, 0.f, 0.f};
    c0 = __builtin_amdgcn_mfma_f32_16x16x32_f16(a0, wb[0], c0, 0, 0, 0);
    c0 = __builtin_amdgcn_mfma_f32_16x16x32_f16(a1, wb[1], c0, 0, 0, 0);
    c0 = __builtin_amdgcn_mfma_f32_16x16x32_f16(a2, wb[2], c0, 0, 0, 0);
    // C rows q*4+r; pool pairs (0,1),(2,3) -> pooled tp = tp0 + mt*8 + q*2 + {0,1}
    int tp = tp0 + mt * 8 + q * 2;
    size_t o = ((size_t)b * T1 + tp) * 16 + ln;
    h1[o] = (__fp16)fmaxf(fmaxf(c0[0], c0[1]) + bv, 0.f);
    h1[o + 16] = (__fp16)fmaxf(fmaxf(c0[2], c0[3]) + bv, 0.f);
  }
}

// ---------------- conv2 + gemm1 fused (MFMA conv): h1 [b][T1][16] -> conv GEMM
// (K=80 pad 96, N=32co) -> relu/pool -> fs LDS -> MFMA @W1 -> xw (fp8, scaled)
// W1 columns are lane-permuted (col = ln*4 + t) so each lane's 4 MFMA calls
// yield 4 ADJACENT output columns -> one packed fp8 dword store per C row.
__global__ __launch_bounds__(256) void conv2_gemm1(const __fp16* __restrict__ h1,
    const float* __restrict__ w, const float* __restrict__ bias,
    const float* __restrict__ W1, const float* __restrict__ dis,
    unsigned char* __restrict__ xw) {
  __shared__ __fp16 xs[520 * ROWW];
  __shared__ __fp16 fs[256 * 40];
  int b = blockIdx.x >> 3;
  int tp0 = (blockIdx.x & 7) * 256;
  int t_base = 2 * tp0 - 2;                    // xs[p] = h1[b][t_base + p][:]
  // stage: straight 16B-chunk copy (h1 is position-major) with bounds zero-fill
  for (int idx = threadIdx.x; idx < 520 * 2; idx += 256) {
    int row = idx >> 1;
    int hf = idx & 1;
    int gt = t_base + row;
    half8 v;
#pragma unroll
    for (int j = 0; j < 8; ++j) v[j] = (__fp16)0.f;
    if (gt >= 0 && gt < T1) v = *(const half8*)(h1 + ((size_t)b * T1 + gt) * 16 + hf * 8);
    *(half8*)(xs + row * ROWW + hf * 8) = v;
  }
  int ln = threadIdx.x & 15;
  int q = (threadIdx.x & 63) >> 4;
  int wib = threadIdx.x >> 6;
  half8 wb[2][3];
#pragma unroll
  for (int nt = 0; nt < 2; ++nt)
#pragma unroll
    for (int ks = 0; ks < 3; ++ks) {
      int kk = ks * 2 + (q >> 1);
#pragma unroll
      for (int j = 0; j < 8; ++j) {
        int ci = (q & 1) * 8 + j;
        float wv = (kk < 5) ? w[((nt * 16 + ln) * 16 + ci) * 5 + kk] : 0.f;
        wb[nt][ks][j] = (__fp16)wv;
      }
    }
  float b20 = bias[ln];
  float b21 = bias[16 + ln];
  __syncthreads();
  int qh = q >> 1, qo = (q & 1) * 8;
#pragma unroll 2
  for (int mtl = 0; mtl < 8; ++mtl) {
    int mt = wib * 8 + mtl;
    int posb = mt * 16 + ln + qh;
    half8 a0 = *(const half8*)(xs + posb * ROWW + qo);
    half8 a1 = *(const half8*)(xs + (posb + 2) * ROWW + qo);
    half8 a2 = *(const half8*)(xs + (posb + 4) * ROWW + qo);
    floatx4 c0 = {0.f, 0.f, 0.f, 0.f};
    floatx4 c1 = {0.f, 0.f, 0.f, 0.f};
    c0 = __builtin_amdgcn_mfma_f32_16x16x32_f16(a0, wb[0][0], c0, 0, 0, 0);
    c0 = __builtin_amdgcn_mfma_f32_16x16x32_f16(a1, wb[0][1], c0, 0, 0, 0);
    c0 = __builtin_amdgcn_mfma_f32_16x16x32_f16(a2, wb[0][2], c0, 0, 0, 0);
    c1 = __builtin_amdgcn_mfma_f32_16x16x32_f16(a0, wb[1][0], c1, 0, 0, 0);
    c1 = __builtin_amdgcn_mfma_f32_16x16x32_f16(a1, wb[1][1], c1, 0, 0, 0);
    c1 = __builtin_amdgcn_mfma_f32_16x16x32_f16(a2, wb[1][2], c1, 0, 0, 0);
    int node = wib * 64 + mtl * 8 + q * 2;     // wave writes only its own rows
    fs[node * 40 + ln] = (__fp16)fmaxf(fmaxf(c0[0], c0[1]) + b20, 0.f);
    fs[(node + 1) * 40 + ln] = (__fp16)fmaxf(fmaxf(c0[2], c0[3]) + b20, 0.f);
    fs[node * 40 + 16 + ln] = (__fp16)fmaxf(fmaxf(c1[0], c1[1]) + b21, 0.f);
    fs[(node + 1) * 40 + 16 + ln] = (__fp16)fmaxf(fmaxf(c1[2], c1[3]) + b21, 0.f);
  }
  // gemm1 epilogue: wave reads only its own fs rows -> no barrier needed.
  // Column-permuted W1: call t gives lane ln output column ln*4 + t.
  half8 bf[4];
#pragma unroll
  for (int t = 0; t < 4; ++t)
#pragma unroll
    for (int j = 0; j < 8; ++j)
      bf[t][j] = (__fp16)W1[(q * 8 + j) * 64 + ln * 4 + t];
  int gnode0 = b * T2 + tp0;
#pragma unroll
  for (int tt = 0; tt < 4; ++tt) {
    int lbase = (wib * 4 + tt) * 16;
    half8 a = *(const half8*)(fs + (lbase + ln) * 40 + q * 8);
    float d[4];
#pragma unroll
    for (int r = 0; r < 4; ++r) d[r] = dis[gnode0 + lbase + q * 4 + r] * FP8_SCALE;
    floatx4 acc[4];
#pragma unroll
    for (int t = 0; t < 4; ++t) {
      floatx4 z = {0.f, 0.f, 0.f, 0.f};
      acc[t] = __builtin_amdgcn_mfma_f32_16x16x32_f16(a, bf[t], z, 0, 0, 0);
    }
#pragma unroll
    for (int r = 0; r < 4; ++r) {
      int u = __builtin_amdgcn_cvt_pk_fp8_f32(acc[0][r] * d[r], acc[1][r] * d[r], 0, 0);
      u = __builtin_amdgcn_cvt_pk_fp8_f32(acc[2][r] * d[r], acc[3][r] * d[r], u, 1);
      *(unsigned*)(xw + (size_t)(gnode0 + lbase + q * 4 + r) * 64 + ln * 4) = (unsigned)u;
    }
  }
}

// ---------------- pass C: partition edges (packed 4B records) into bucket regions
__global__ __launch_bounds__(256) void partition_pairs(const int* __restrict__ ei, int E,
    int* __restrict__ rcnt, int* __restrict__ gpairs) {
  __shared__ int lcnt[NCB];
  __shared__ int lpk[NCB * PC_CAP];
  if (threadIdx.x < NCB) lcnt[threadIdx.x] = 0;
  __syncthreads();
  int e0 = blockIdx.x * PC_EDGES;
#pragma unroll
  for (int j = 0; j < PC_EDGES / 256; ++j) {
    int e = e0 + j * 256 + threadIdx.x;
    if (e < E) {
      int r = ei[e];
      int c = ei[E + e];
      int cb = c >> CB_SHIFT;
      int pk = r | ((c & (CB_TGT - 1)) << 17);
      int slot = atomicAdd(&lcnt[cb], 1);
      if (slot < PC_CAP) {
        lpk[cb * PC_CAP + slot] = pk;
      } else {
        int pos = atomicAdd(&rcnt[cb], 1);
        if (pos < RCAP) gpairs[(size_t)cb * RCAP + pos] = pk;
      }
    }
  }
  __syncthreads();
  int t = threadIdx.x;
  if (t < NCB) {
    int n = lcnt[t];
    if (n > PC_CAP) n = PC_CAP;
    if (n > 0) {
      int base = atomicAdd(&rcnt[t], n);
      int* dst = gpairs + (size_t)t * RCAP;
      for (int k = 0; k < n; ++k) {
        int p = base + k;
        if (p < RCAP) dst[p] = lpk[t * PC_CAP + k];
      }
    }
  }
}

// ---------------- pass D: per coarse bucket, exact-degree CSR via wave-scans
__global__ __launch_bounds__(512) void build_csr(const int* __restrict__ gpairs,
    const int* __restrict__ rcnt, int* __restrict__ ebuf,
    int* __restrict__ estart, int* __restrict__ ecnt, float* __restrict__ dis) {
  __shared__ int deg[CB_TGT];
  __shared__ int cur[CB_TGT];
  __shared__ int sc[CB_TGT];
  __shared__ int wsum[8];
  int b = blockIdx.x;
  int t = threadIdx.x;
  deg[t] = 0;
  cur[t] = 0;
  __syncthreads();
  int m = rcnt[b];
  if (m > RCAP) m = RCAP;
  const int* reg = gpairs + (size_t)b * RCAP;
  for (int k = t; k < m; k += 512)
    atomicAdd(&deg[(reg[k] >> 17) & (CB_TGT - 1)], 1);
  __syncthreads();
  int d = deg[t];
  int lane = t & 63;
  int wv = t >> 6;
  int sum = d;
#pragma unroll
  for (int off = 1; off < 64; off <<= 1) {
    int v = __shfl_up(sum, off, 64);
    if (lane >= off) sum += v;
  }
  if (lane == 63) wsum[wv] = sum;
  __syncthreads();
  int prefix = 0;
#pragma unroll
  for (int i = 0; i < 8; ++i) prefix += (i < wv) ? wsum[i] : 0;
  int excl = prefix + sum - d;
  int gi = (b << CB_SHIFT) + t;
  int base = b * RCAP;
  estart[gi] = base + excl;
  ecnt[gi] = d;
  dis[gi] = rsqrtf((float)d + 1.0f);
  sc[t] = excl;
  __syncthreads();
  for (int k = t; k < m; k += 512) {
    int p = reg[k];
    int lc = (p >> 17) & (CB_TGT - 1);
    int off = atomicAdd(&cur[lc], 1);
    ebuf[base + sc[lc] + off] = p & PK_RMASK;
  }
}

// ======== gather macro (fp8 rows, 64 B = 1 cache line): staged edge span,
// 16-edge windows. wave layout: es = lane>>4 (4 edge slots), ch = lane&15
// (features ch*4..ch*4+3 = one dword). Full windows carry NO bounds checks;
// only the tail window selects the zero row per slot. Each dword converts
// via 2x v_cvt_pk_f32_fp8 into float2 accumulators (v_pk_add_f32).
#define GATHER_NODE(c_, stl_, ALO, AHI)                                         \
  {                                                                             \
    int sb_ = (stl_) + es;                                                      \
    int nf_ = (c_) >> 4;                                                        \
    for (int it = 0; it < nf_; ++it) {                                          \
      unsigned wv_[4];                                                          \
      _Pragma("unroll")                                                         \
      for (int j = 0; j < 4; ++j) {                                             \
        unsigned r = (unsigned)sidx[sb_ + (it << 4) + j * 4];                   \
        wv_[j] = *(const unsigned*)(tab + ((r << 6) + ch4));                    \
      }                                                                         \
      _Pragma("unroll")                                                         \
      for (int j = 0; j < 4; ++j) {                                             \
        ALO += __builtin_amdgcn_cvt_pk_f32_fp8(wv_[j], 0);                      \
        AHI += __builtin_amdgcn_cvt_pk_f32_fp8(wv_[j], 1);                      \
      }                                                                         \
    }                                                                           \
    if ((c_) & 15) {                                                            \
      int s0_ = nf_ << 4;                                                       \
      unsigned wv_[4];                                                          \
      _Pragma("unroll")                                                         \
      for (int j = 0; j < 4; ++j) {                                             \
        int k = s0_ + j * 4 + es;                                               \
        unsigned r = (unsigned)sidx[(stl_) + k];                                \
        unsigned off = (k < (c_)) ? ((r << 6) + ch4) : zoff;                    \
        wv_[j] = *(const unsigned*)(tab + off);                                 \
      }                                                                         \
      _Pragma("unroll")                                                         \
      for (int j = 0; j < 4; ++j) {                                             \
        ALO += __builtin_amdgcn_cvt_pk_f32_fp8(wv_[j], 0);                      \
        AHI += __builtin_amdgcn_cvt_pk_f32_fp8(wv_[j], 1);                      \
      }                                                                         \
    }                                                                           \
  }

// ---------------- agg1 + gemm2 fused (fp8 table, staged edge span)
__global__ __launch_bounds__(256) void agg1_gemm2(const unsigned char* __restrict__ tab,
    const int* __restrict__ ebuf, const int* __restrict__ estart,
    const int* __restrict__ ecnt, const float* __restrict__ dis,
    const float* __restrict__ bias, const float* __restrict__ W2,
    unsigned char* __restrict__ xw2, int N) {
  __shared__ __fp16 g1s[16 * 72];
  __shared__ int sidx[EC + 16];   // +16: tail window may over-read in-bounds
  __shared__ int sst[16], scn[16];
  int t = threadIdx.x;
  int base16 = blockIdx.x * 16;
  if (t < 16) {
    sst[t] = estart[base16 + t];
    scn[t] = ecnt[base16 + t];
  }
  __syncthreads();
  int span0 = sst[0];
  int total = sst[15] + scn[15] - span0;
  if (total > EC) total = EC;
  for (int k = t; k < total; k += 256) sidx[k] = ebuf[span0 + k];
  __syncthreads();
  int lane = t & 63;
  int es = lane >> 4;
  int ch = lane & 15;
  int wib = t >> 6;
  unsigned ch4 = (unsigned)ch * 4u;
  unsigned zoff = ((unsigned)ZROW << 6) + ch4;
  float4 bv = *(const float4*)(bias + ch * 4);
#pragma unroll
  for (int jj = 0; jj < 4; ++jj) {
    int il = wib * 4 + jj;
    int i = base16 + il;
    int stl = sst[il] - span0;
    int c = scn[il];
    if (stl + c > EC) c = (EC > stl) ? (EC - stl) : 0;
    float di = dis[i] * FP8_SINV;
    floatx2 aLO = {0.f, 0.f}, aHI = {0.f, 0.f};
    GATHER_NODE(c, stl, aLO, aHI)
    float ax = aLO.x, ay = aLO.y, az = aHI.x, aw = aHI.y;
    ax += __shfl_xor(ax, 16, 64); ax += __shfl_xor(ax, 32, 64);
    ay += __shfl_xor(ay, 16, 64); ay += __shfl_xor(ay, 32, 64);
    az += __shfl_xor(az, 16, 64); az += __shfl_xor(az, 32, 64);
    aw += __shfl_xor(aw, 16, 64); aw += __shfl_xor(aw, 32, 64);
    unsigned sw = *(const unsigned*)(tab + (((unsigned)i << 6) + ch4));
    floatx2 slo = __builtin_amdgcn_cvt_pk_f32_fp8(sw, 0);
    floatx2 shi = __builtin_amdgcn_cvt_pk_f32_fp8(sw, 1);
    if (es == 0) {
      half4v r;
      r[0] = (__fp16)fmaxf((ax + slo.x) * di + bv.x, 0.f);
      r[1] = (__fp16)fmaxf((ay + slo.y) * di + bv.y, 0.f);
      r[2] = (__fp16)fmaxf((az + shi.x) * di + bv.z, 0.f);
      r[3] = (__fp16)fmaxf((aw + shi.y) * di + bv.w, 0.f);
      *(half4v*)(g1s + il * 72 + ch * 4) = r;
    }
  }
  __syncthreads();
  // gemm2 epilogue: wave wib computes output columns wib*16..wib*16+15
  int m = lane & 15;
  int q = lane >> 4;
  half8 b0, b1;
#pragma unroll
  for (int j = 0; j < 8; ++j) {
    b0[j] = (__fp16)W2[(q * 8 + j) * 64 + wib * 16 + m];
    b1[j] = (__fp16)W2[(32 + q * 8 + j) * 64 + wib * 16 + m];
  }
  half8 a0 = *(const half8*)(g1s + m * 72 + q * 8);
  half8 a1 = *(const half8*)(g1s + m * 72 + 32 + q * 8);
  floatx4 acc = {0.f, 0.f, 0.f, 0.f};
  acc = __builtin_amdgcn_mfma_f32_16x16x32_f16(a0, b0, acc, 0, 0, 0);
  acc = __builtin_amdgcn_mfma_f32_16x16x32_f16(a1, b1, acc, 0, 0, 0);
  float sv[4];
#pragma unroll
  for (int r = 0; r < 4; ++r)
    sv[r] = acc[r] * dis[base16 + q * 4 + r] * FP8_SCALE;
  int u = __builtin_amdgcn_cvt_pk_fp8_f32(sv[0], sv[1], 0, 0);
  u = __builtin_amdgcn_cvt_pk_fp8_f32(sv[2], sv[3], u, 1);
#pragma unroll
  for (int r = 0; r < 4; ++r) {
    int node = base16 + q * 4 + r;
    xw2[(size_t)node * 64 + wib * 16 + m] = (unsigned char)(((unsigned)u) >> (8 * r));
  }
}

// ---------------- GCN aggregate layer-2 (fp8 table, staged span) + mean-pool
__global__ __launch_bounds__(256) void gcn_aggregate_pool(const unsigned char* __restrict__ tab,
    const int* __restrict__ ebuf, const int* __restrict__ estart,
    const int* __restrict__ ecnt, const float* __restrict__ dis,
    const float* __restrict__ bias, float* __restrict__ pool, int N) {
  __shared__ float4 red[4][16];
  __shared__ int sidx[EC + 16];   // +16: tail window may over-read in-bounds
  __shared__ int sst[16], scn[16];
  int t = threadIdx.x;
  int base16 = blockIdx.x * 16;
  if (t < 16) {
    sst[t] = estart[base16 + t];
    scn[t] = ecnt[base16 + t];
  }
  __syncthreads();
  int span0 = sst[0];
  int total = sst[15] + scn[15] - span0;
  if (total > EC) total = EC;
  for (int k = t; k < total; k += 256) sidx[k] = ebuf[span0 + k];
  __syncthreads();
  int lane = t & 63;
  int es = lane >> 4;
  int ch = lane & 15;
  int wib = t >> 6;
  unsigned ch4 = (unsigned)ch * 4u;
  unsigned zoff = ((unsigned)ZROW << 6) + ch4;
  float4 bv = *(const float4*)(bias + ch * 4);
  float px = 0.f, py = 0.f, pz = 0.f, pw = 0.f;
#pragma unroll
  for (int jj = 0; jj < 4; ++jj) {
    int il = wib * 4 + jj;
    int i = base16 + il;
    int stl = sst[il] - span0;
    int c = scn[il];
    if (stl + c > EC) c = (EC > stl) ? (EC - stl) : 0;
    float di = dis[i] * FP8_SINV;
    floatx2 aLO = {0.f, 0.f}, aHI = {0.f, 0.f};
    GATHER_NODE(c, stl, aLO, aHI)
    float ax = aLO.x, ay = aLO.y, az = aHI.x, aw = aHI.y;
    ax += __shfl_xor(ax, 16, 64); ax += __shfl_xor(ax, 32, 64);
    ay += __shfl_xor(ay, 16, 64); ay += __shfl_xor(ay, 32, 64);
    az += __shfl_xor(az, 16, 64); az += __shfl_xor(az, 32, 64);
    aw += __shfl_xor(aw, 16, 64); aw += __shfl_xor(aw, 32, 64);
    unsigned sw = *(const unsigned*)(tab + (((unsigned)i << 6) + ch4));
    floatx2 slo = __builtin_amdgcn_cvt_pk_f32_fp8(sw, 0);
    floatx2 shi = __builtin_amdgcn_cvt_pk_f32_fp8(sw, 1);
    px += fmaxf((ax + slo.x) * di + bv.x, 0.f);
    py += fmaxf((ay + slo.y) * di + bv.y, 0.f);
    pz += fmaxf((az + shi.x) * di + bv.z, 0.f);
    pw += fmaxf((aw + shi.y) * di + bv.w, 0.f);
  }
  if (es == 0) red[wib][ch] = make_float4(px, py, pz, pw);
  __syncthreads();
  if (threadIdx.x < 64) {
    int f = threadIdx.x;
    int c4 = f >> 2, j4 = f & 3;
    const float* r0 = (const float*)&red[0][c4];
    const float* r1 = (const float*)&red[1][c4];
    const float* r2 = (const float*)&red[2][c4];
    const float* r3 = (const float*)&red[3][c4];
    float sum = r0[j4] + r1[j4] + r2[j4] + r3[j4];
    int b = (blockIdx.x * 16) >> 11;
    atomicAdd(&pool[b * 64 + f], sum);
  }
}

// ---------------- classifier: out[b] = (pool[b]/2048) @ cls_w + cls_b
__global__ __launch_bounds__(64) void classify(const float* __restrict__ pool,
    const float* __restrict__ cw, const float* __restrict__ cb,
    float* __restrict__ out) {
  __shared__ float pl[64];
  int b = blockIdx.x;
  int t = threadIdx.x;
  pl[t] = pool[b * 64 + t] * (1.0f / (float)T2);
  __syncthreads();
  if (t < NOUT) {
    float a = cb[t];
#pragma unroll
    for (int k = 0; k < 64; ++k) a += pl[k] * cw[k * NOUT + t];
    out[b * NOUT + t] = a;
  }
}

extern "C" void kernel_launch(void* const* d_in, const int* in_sizes, int n_in,
                              void* d_out, int out_size, void* d_ws, size_t ws_size,
                              hipStream_t stream) {
  const float* x    = (const float*)d_in[0];
  const int*   ei   = (const int*)d_in[1];
  const float* c1w  = (const float*)d_in[2];
  const float* c1b  = (const float*)d_in[3];
  const float* c2w  = (const float*)d_in[4];
  const float* c2b  = (const float*)d_in[5];
  const float* g1w  = (const float*)d_in[6];
  const float* g1b  = (const float*)d_in[7];
  const float* g2w  = (const float*)d_in[8];
  const float* g2b  = (const float*)d_in[9];
  const float* cw   = (const float*)d_in[10];
  const float* cb   = (const float*)d_in[11];
  float* out = (float*)d_out;
  int E = in_sizes[1] / 2;
  const int N = N_NODES;

  // workspace layout (bytes); xw/xw2 are fp8 tables with N+1 rows of 64 B
  // (last = zero row). Offsets kept from the fp16 layout (shrunk in place).
  char* ws = (char*)d_ws;
  int*    gpairs = (int*)(ws);                     //  9,437,184 (packed 4B)
  int*    ebuf   = (int*)(ws + 9437184);           //  9,437,184
  int*    rcnt   = (int*)(ws + 18874368);          //      4,096
  int*    estart = (int*)(ws + 18878464);          //    524,288
  int*    ecnt   = (int*)(ws + 19402752);          //    524,288
  float*  dis    = (float*)(ws + 19927040);        //    524,288
  float*  pool   = (float*)(ws + 20451328);        //     16,384
  unsigned char* xw  = (unsigned char*)(ws + 20467712);  // 8,388,672 fp8
  unsigned char* xw2 = (unsigned char*)(ws + 37245184);  // 8,388,672 fp8
  __fp16* h1     = (__fp16*)(ws + 54022656);       //  8,388,608 ([b][T1][16] fp16)

  hipMemsetAsync(rcnt, 0, NCB * sizeof(int), stream);
  hipMemsetAsync(pool, 0, BATCH * HID * sizeof(float), stream);
  hipMemsetAsync(xw + (size_t)N * 64, 0, 64, stream);   // zero row
  hipMemsetAsync(xw2 + (size_t)N * 64, 0, 64, stream);  // zero row

  conv1_kernel<<<dim3(BATCH * 16), dim3(256), 0, stream>>>(x, c1w, c1b, h1);
  partition_pairs<<<dim3((E + PC_EDGES - 1) / PC_EDGES), dim3(256), 0, stream>>>(ei, E, rcnt, gpairs);
  build_csr<<<dim3(NCB), dim3(512), 0, stream>>>(gpairs, rcnt, ebuf, estart, ecnt, dis);

  conv2_gemm1<<<dim3(BATCH * 8), dim3(256), 0, stream>>>(h1, c2w, c2b, g1w, dis, xw);
  agg1_gemm2<<<dim3(N / 16), dim3(256), 0, stream>>>(xw, ebuf, estart, ecnt, dis, g1b, g2w, xw2, N);
  gcn_aggregate_pool<<<dim3(N / 16), dim3(256), 0, stream>>>(xw2, ebuf, estart, ecnt, dis, g2b, pool, N);

  classify<<<dim3(BATCH), dim3(64), 0, stream>>>(pool, cw, cb, out);
}